// Round 4
// baseline (257.100 us; speedup 1.0000x reference)
//
#include <hip/hip_runtime.h>
#include <hip/hip_bf16.h>

#define IMG 28
#define KX 784             // true K = 28*28
#define KT 25              // k-tiles of 32 -> K padded to 800
#define NT 13              // n-tiles of 16 -> N padded to 208
#define NH 200
#define NOUT 10
#define WV 4               // waves per block
#define MW 16              // images per wave (one 16-row m-frag)

typedef __attribute__((ext_vector_type(8))) short bf16x8;
typedef __attribute__((ext_vector_type(4))) float f32x4;

static __device__ __forceinline__ unsigned short bf16_bits(float v) {
    __hip_bfloat16 b = __float2bfloat16(v);
    return *(unsigned short*)&b;
}

static __device__ __forceinline__ bf16x8 cvt8(float4 a, float4 b) {
    bf16x8 r;
    r[0] = (short)bf16_bits(a.x); r[1] = (short)bf16_bits(a.y);
    r[2] = (short)bf16_bits(a.z); r[3] = (short)bf16_bits(a.w);
    r[4] = (short)bf16_bits(b.x); r[5] = (short)bf16_bits(b.y);
    r[6] = (short)bf16_bits(b.z); r[7] = (short)bf16_bits(b.w);
    return r;
}

// --- build W_eff = w0 composed with conv, packed in MFMA fragment order ---
// NEW layout: plane-major by kt so per-kt B reads are contiguous:
// Bf[((kt*NT + nt)*64 + L)*8 + j] = W_eff[nt*16+(L&15)][kt*32+(L>>4)*8+j], 0-padded.
__global__ void build_weff(const float* __restrict__ w0, const float* __restrict__ cw,
                           __hip_bfloat16* __restrict__ Bf) {
    int idx = blockIdx.x * blockDim.x + threadIdx.x;
    if (idx >= NT * KT * 512) return;
    int j = idx & 7, L = (idx >> 3) & 63;
    int plane = idx >> 9;                  // 0..324
    int nt = plane % NT, kt = plane / NT;
    int n = nt * 16 + (L & 15);
    int k = kt * 32 + ((L >> 4) << 3) + j;
    float acc = 0.f;
    if (n < NH && k < KX) {
        int u = k / IMG, v = k - u * IMG;
#pragma unroll
        for (int i = 0; i < 3; ++i) {
#pragma unroll
            for (int jj = 0; jj < 3; ++jj) {
                int r = u - i, c = v - jj;
                if (r >= 0 && r < 26 && c >= 0 && c < 26)
                    acc += cw[i * 3 + jj] * w0[n * 676 + r * 26 + c];
            }
        }
    }
    Bf[idx] = __float2bfloat16(acc);
}

// Wave-autonomous fused kernel. Per wave: 16 images, kt-outer / nt-inner GEMM.
// A: direct global->reg (16 full 128B lines per load instr), 2-deep ring.
// B: 13-slot register ring over [kt][nt]-packed planes, L2/L1-resident.
// No __syncthreads anywhere; per-kt raw s_barrier only paces the 4 waves for
// L1 sharing of B (correctness never depends on it).
// (256,2): 2 blocks/CU -> 8 waves/CU, 256-VGPR cap, LDS 53,248B (2/CU fits).
__global__ __launch_bounds__(256, 2) void gemm_fused_kernel(
    const float* __restrict__ x,            // [32768, 784]
    const __hip_bfloat16* __restrict__ Bf,  // [kt][nt]-packed W_eff
    const float* __restrict__ b0,           // [200]
    const float* __restrict__ w1,           // [10, 200]
    const float* __restrict__ b1,           // [10]
    float* __restrict__ out)                // [32768, 10]
{
    __shared__ __align__(16) float H[WV][MW][208];   // wave-private h rows

    const int tid  = threadIdx.x;
    const int wave = tid >> 6;
    const int L    = tid & 63;
    const int lm   = L & 15;
    const int q    = L >> 4;
    const int img0 = (blockIdx.x * WV + wave) * MW;

    // lane's A base: row img0+lm, k-offset q*8 (A-frag: row=L&15, k=(L>>4)*8+j)
    const float* xl = x + (size_t)(img0 + lm) * KX + q * 8;
    const bf16x8* bb = (const bf16x8*)Bf + L;

    f32x4 acc[NT];
#pragma unroll
    for (int n = 0; n < NT; ++n) acc[n] = (f32x4){0.f, 0.f, 0.f, 0.f};

    bf16x8 b[NT];                      // B ring: plane kt resident
    float4 aE0, aE1, aO0, aO1;         // A ring: 2 kt in flight (parity slots)

    // ---- prologue: issue A(0), A(1), B plane 0 ----
    aE0 = *(const float4*)(xl);
    aE1 = *(const float4*)(xl + 4);
    aO0 = *(const float4*)(xl + 32);
    aO1 = *(const float4*)(xl + 36);
#pragma unroll
    for (int n = 0; n < NT; ++n) b[n] = bb[n * 64];
    __builtin_amdgcn_sched_barrier(0);

    // ---- main loop: fully unrolled, all array indices compile-time ----
#pragma unroll
    for (int kt = 0; kt < KT; ++kt) {
        // convert A(kt): waits only its own 2 loads (issued 2 iters ago)
        bf16x8 a = (kt & 1) ? cvt8(aO0, aO1) : cvt8(aE0, aE1);
        __builtin_amdgcn_s_barrier();          // pace 4 waves onto same B plane
#pragma unroll
        for (int n = 0; n < NT; ++n) {
            bf16x8 cur = b[n];
            if (kt + 1 < KT) b[n] = bb[((kt + 1) * NT + n) * 64];
            acc[n] = __builtin_amdgcn_mfma_f32_16x16x32_bf16(a, cur, acc[n], 0, 0, 0);
        }
        // issue A(kt+2) AFTER B(kt+1): B-waits never drain a young HBM load
        if (kt + 2 < KT) {
            const float* p = xl + (kt + 2) * 32;
            float4 n0 = {0.f, 0.f, 0.f, 0.f}, n1 = {0.f, 0.f, 0.f, 0.f};
            if ((kt + 2 < KT - 1) || (q < 2)) {   // kt=24: cols 784..799 are pad
                n0 = *(const float4*)(p);
                n1 = *(const float4*)(p + 4);
            }
            if (kt & 1) { aO0 = n0; aO1 = n1; } else { aE0 = n0; aE1 = n1; }
        }
        __builtin_amdgcn_sched_barrier(0);     // pin the per-iter pipeline shape
    }

    // ---- epilogue: h = relu(acc + b0) -> wave-private LDS rows ----
#pragma unroll
    for (int n = 0; n < NT; ++n) {
        int col = n * 16 + lm;
        if (col < NH) {
            float bv = b0[col];
#pragma unroll
            for (int r = 0; r < 4; ++r) {
                float v = acc[n][r] + bv;
                H[wave][q * 4 + r][col] = v > 0.f ? v : 0.f;
            }
        }
    }
    __builtin_amdgcn_s_barrier();   // (uniform) belt+suspenders before H reads

    // ---- FC1: lane (lm,q) -> img=img0+lm, j in {q, q+4, q+8} ----
    const float* Hrow = &H[wave][lm][0];
    float fj0 = 0.f, fj1 = 0.f, fj2 = 0.f;
    const bool j2ok = (q < 2);      // q+8 < 10
#pragma unroll
    for (int c = 0; c < NH / 4; ++c) {
        float4 h4 = *(const float4*)(Hrow + c * 4);
        float4 w40 = *(const float4*)(w1 + q * NH + c * 4);
        float4 w41 = *(const float4*)(w1 + (q + 4) * NH + c * 4);
        fj0 += h4.x * w40.x + h4.y * w40.y + h4.z * w40.z + h4.w * w40.w;
        fj1 += h4.x * w41.x + h4.y * w41.y + h4.z * w41.z + h4.w * w41.w;
        if (j2ok) {
            float4 w42 = *(const float4*)(w1 + (q + 8) * NH + c * 4);
            fj2 += h4.x * w42.x + h4.y * w42.y + h4.z * w42.z + h4.w * w42.w;
        }
    }
    float* orow = out + (size_t)(img0 + lm) * NOUT;
    orow[q]     = fj0 + b1[q];
    orow[q + 4] = fj1 + b1[q + 4];
    if (j2ok) orow[q + 8] = fj2 + b1[q + 8];
}

extern "C" void kernel_launch(void* const* d_in, const int* in_sizes, int n_in,
                              void* d_out, int out_size, void* d_ws, size_t ws_size,
                              hipStream_t stream) {
    const float* x   = (const float*)d_in[0];
    const float* cw  = (const float*)d_in[1];
    const float* w0  = (const float*)d_in[2];
    const float* b0  = (const float*)d_in[3];
    const float* w1  = (const float*)d_in[4];
    const float* b1  = (const float*)d_in[5];
    float* out = (float*)d_out;

    __hip_bfloat16* Bf = (__hip_bfloat16*)d_ws;  // 13*25*512*2 = 332,800 B

    const int pack_elems = NT * KT * 512;
    build_weff<<<(pack_elems + 255) / 256, 256, 0, stream>>>(w0, cw, Bf);

    // 32768 images / (4 waves * 16 images) = 512 blocks = 2/CU, all resident
    gemm_fused_kernel<<<32768 / (WV * MW), 256, 0, stream>>>(x, Bf, b0, w1, b1, out);
}

// Round 5
// 236.666 us; speedup vs baseline: 1.0863x; 1.0863x over previous
//
#include <hip/hip_runtime.h>
#include <hip/hip_bf16.h>

#define IMG 28
#define KX 784             // true K = 28*28
#define KT 25              // k-tiles of 32 -> K padded to 800
#define NT 13              // n-tiles of 16 -> N padded to 208
#define NH 200
#define NOUT 10
#define WV 4               // waves per block
#define MW 16              // images per wave (one 16-row m-frag)
#define HSTRIDE 212        // fp32 elems per LDS h row (208 + 4: stride%32=20 -> no 8-way conflict)
#define NPLANES (KT * NT)  // 325 B-fragments in the flat stream

typedef __attribute__((ext_vector_type(8))) short bf16x8;
typedef __attribute__((ext_vector_type(4))) float f32x4;

static __device__ __forceinline__ unsigned short bf16_bits(float v) {
    __hip_bfloat16 b = __float2bfloat16(v);
    return *(unsigned short*)&b;
}

static __device__ __forceinline__ bf16x8 cvt8(float4 a, float4 b) {
    bf16x8 r;
    r[0] = (short)bf16_bits(a.x); r[1] = (short)bf16_bits(a.y);
    r[2] = (short)bf16_bits(a.z); r[3] = (short)bf16_bits(a.w);
    r[4] = (short)bf16_bits(b.x); r[5] = (short)bf16_bits(b.y);
    r[6] = (short)bf16_bits(b.z); r[7] = (short)bf16_bits(b.w);
    return r;
}

// --- build W_eff = w0 composed with conv, packed in MFMA fragment order ---
// Plane-major by kt so per-kt B reads are one contiguous 13 KB stream:
// Bf[((kt*NT + nt)*64 + L)*8 + j] = W_eff[nt*16+(L&15)][kt*32+(L>>4)*8+j], 0-padded.
__global__ void build_weff(const float* __restrict__ w0, const float* __restrict__ cw,
                           __hip_bfloat16* __restrict__ Bf) {
    int idx = blockIdx.x * blockDim.x + threadIdx.x;
    if (idx >= NPLANES * 512) return;
    int j = idx & 7, L = (idx >> 3) & 63;
    int plane = idx >> 9;                  // 0..324
    int nt = plane % NT, kt = plane / NT;
    int n = nt * 16 + (L & 15);
    int k = kt * 32 + ((L >> 4) << 3) + j;
    float acc = 0.f;
    if (n < NH && k < KX) {
        int u = k / IMG, v = k - u * IMG;
#pragma unroll
        for (int i = 0; i < 3; ++i) {
#pragma unroll
            for (int jj = 0; jj < 3; ++jj) {
                int r = u - i, c = v - jj;
                if (r >= 0 && r < 26 && c >= 0 && c < 26)
                    acc += cw[i * 3 + jj] * w0[n * 676 + r * 26 + c];
            }
        }
    }
    Bf[idx] = __float2bfloat16(acc);
}

// Wave-autonomous fused kernel. Per wave: 16 images, kt-outer / nt-inner GEMM.
// A: direct global->reg (16 full 128B lines per load instr), 2-kt-deep ring.
// B: rolling 8-slot register ring over the flat [kt][nt] stream (L1/L2-resident;
//    per-kt s_barrier paces the 4 waves onto the same plane for L1 sharing).
// Per-iter issue order (B loads, then A loads) keeps the vmcnt FIFO clean:
// a B-wait never has to drain a younger 900-cycle HBM A-load.
// (256,1): full 512-reg budget/wave -> NO spill (~160 used); HW still fits
// 2 blocks/CU from actual usage.
__global__ __launch_bounds__(256, 1) void gemm_fused_kernel(
    const float* __restrict__ x,            // [32768, 784]
    const __hip_bfloat16* __restrict__ Bf,  // [kt][nt]-packed W_eff
    const float* __restrict__ b0,           // [200]
    const float* __restrict__ w1,           // [10, 200]
    const float* __restrict__ b1,           // [10]
    float* __restrict__ out)                // [32768, 10]
{
    __shared__ __align__(16) float H[WV][MW][HSTRIDE];   // 54,272 B, wave-private rows

    const int tid  = threadIdx.x;
    const int wave = tid >> 6;
    const int L    = tid & 63;
    const int lm   = L & 15;
    const int q    = L >> 4;
    const int img0 = (blockIdx.x * WV + wave) * MW;

    // lane's A base: row img0+lm, k-offset q*8 (A-frag: row=L&15, k=(L>>4)*8+j)
    const float* xl = x + (size_t)(img0 + lm) * KX + q * 8;
    const bf16x8* bb = (const bf16x8*)Bf + L;

    f32x4 acc[NT];
#pragma unroll
    for (int n = 0; n < NT; ++n) acc[n] = (f32x4){0.f, 0.f, 0.f, 0.f};

    bf16x8 br[8];                      // rolling B ring (32 VGPRs)
    float4 aE0, aE1, aO0, aO1;         // A ring: 2 kt in flight (parity slots)

    // ---- prologue: issue A(0), A(1), B stream idx 0..7 ----
    aE0 = *(const float4*)(xl);
    aE1 = *(const float4*)(xl + 4);
    aO0 = *(const float4*)(xl + 32);
    aO1 = *(const float4*)(xl + 36);
#pragma unroll
    for (int i = 0; i < 8; ++i) br[i] = bb[i * 64];
    __builtin_amdgcn_sched_barrier(0);

    // ---- main loop: fully unrolled, all ring indices compile-time ----
#pragma unroll
    for (int kt = 0; kt < KT; ++kt) {
        // convert A(kt): waits only its own 2 loads (issued 2 iters ago)
        bf16x8 a = (kt & 1) ? cvt8(aO0, aO1) : cvt8(aE0, aE1);
        __builtin_amdgcn_s_barrier();          // pace 4 waves onto same B plane
#pragma unroll
        for (int n = 0; n < NT; ++n) {
            const int idx = kt * NT + n;       // compile-time after unroll
            bf16x8 cur = br[idx & 7];
            if (idx + 8 < NPLANES) br[idx & 7] = bb[(idx + 8) * 64];
            acc[n] = __builtin_amdgcn_mfma_f32_16x16x32_bf16(a, cur, acc[n], 0, 0, 0);
        }
        // issue A(kt+2) AFTER this iter's B loads: clean FIFO ordering
        if (kt + 2 < KT) {
            const float* p = xl + (kt + 2) * 32;
            float4 n0 = {0.f, 0.f, 0.f, 0.f}, n1 = {0.f, 0.f, 0.f, 0.f};
            if ((kt + 2 < KT - 1) || (q < 2)) {   // kt=24: cols 784..799 are pad
                n0 = *(const float4*)(p);
                n1 = *(const float4*)(p + 4);
            }
            if (kt & 1) { aO0 = n0; aO1 = n1; } else { aE0 = n0; aE1 = n1; }
        }
        __builtin_amdgcn_sched_barrier(0);     // pin the per-iter pipeline shape
    }

    // ---- epilogue: h = relu(acc + b0) -> wave-private LDS rows ----
#pragma unroll
    for (int n = 0; n < NT; ++n) {
        int col = n * 16 + lm;
        if (col < NH) {
            float bv = b0[col];
#pragma unroll
            for (int r = 0; r < 4; ++r) {
                float v = acc[n][r] + bv;
                H[wave][q * 4 + r][col] = v > 0.f ? v : 0.f;
            }
        }
    }
    __builtin_amdgcn_s_barrier();   // uniform; H rows are wave-private anyway

    // ---- FC1: lane (lm,q) -> img=img0+lm, j in {q, q+4, q+8} ----
    const float* Hrow = &H[wave][lm][0];
    float fj0 = 0.f, fj1 = 0.f, fj2 = 0.f;
    const bool j2ok = (q < 2);      // q+8 < 10
#pragma unroll
    for (int c = 0; c < NH / 4; ++c) {
        float4 h4 = *(const float4*)(Hrow + c * 4);
        float4 w40 = *(const float4*)(w1 + q * NH + c * 4);
        float4 w41 = *(const float4*)(w1 + (q + 4) * NH + c * 4);
        fj0 += h4.x * w40.x + h4.y * w40.y + h4.z * w40.z + h4.w * w40.w;
        fj1 += h4.x * w41.x + h4.y * w41.y + h4.z * w41.z + h4.w * w41.w;
        if (j2ok) {
            float4 w42 = *(const float4*)(w1 + (q + 8) * NH + c * 4);
            fj2 += h4.x * w42.x + h4.y * w42.y + h4.z * w42.z + h4.w * w42.w;
        }
    }
    float* orow = out + (size_t)(img0 + lm) * NOUT;
    orow[q]     = fj0 + b1[q];
    orow[q + 4] = fj1 + b1[q + 4];
    if (j2ok) orow[q + 8] = fj2 + b1[q + 8];
}

extern "C" void kernel_launch(void* const* d_in, const int* in_sizes, int n_in,
                              void* d_out, int out_size, void* d_ws, size_t ws_size,
                              hipStream_t stream) {
    const float* x   = (const float*)d_in[0];
    const float* cw  = (const float*)d_in[1];
    const float* w0  = (const float*)d_in[2];
    const float* b0  = (const float*)d_in[3];
    const float* w1  = (const float*)d_in[4];
    const float* b1  = (const float*)d_in[5];
    float* out = (float*)d_out;

    __hip_bfloat16* Bf = (__hip_bfloat16*)d_ws;  // 325*512*2 = 332,800 B

    const int pack_elems = NPLANES * 512;
    build_weff<<<(pack_elems + 255) / 256, 256, 0, stream>>>(w0, cw, Bf);

    // 32768 images / (4 waves * 16 images) = 512 blocks
    gemm_fused_kernel<<<32768 / (WV * MW), 256, 0, stream>>>(x, Bf, b0, w1, b1, out);
}

// Round 7
// 186.551 us; speedup vs baseline: 1.3782x; 1.2686x over previous
//
#include <hip/hip_runtime.h>
#include <hip/hip_bf16.h>

#define IMG 28
#define KX 784             // true K = 28*28
#define KT 25              // k-tiles of 32 -> K padded to 800
#define NT 13              // n-tiles of 16 -> N padded to 208; waves {2,2,2,2,2,1,1,1}
#define NH 200
#define NOUT 10
#define MT 32              // images per block
#define CHK 5              // k-tiles per chunk
#define NCH 5              // chunks (5*5 = KT)
#define CHS 168            // bf16 elems per LDS A row in a chunk buf (160 + 8 pad; 336B rows, 16B-aligned)
#define HSTRIDE 212        // fp32 elems per LDS h row (212%32=20 -> no 8/16-way conflict; 0 conflicts in r5)
#define F4C (MT * CHK * 8) // 1280 float4 per chunk (32 rows x 40 f4)

typedef __attribute__((ext_vector_type(8))) short bf16x8;
typedef __attribute__((ext_vector_type(4))) float f32x4;
typedef __attribute__((ext_vector_type(4))) short s16x4;

static __device__ __forceinline__ unsigned short bf16_bits(float v) {
    __hip_bfloat16 b = __float2bfloat16(v);
    return *(unsigned short*)&b;
}

// Raw barrier: drains MY ds_writes (lgkmcnt) for cross-wave visibility but NOT
// vmcnt -- B-ring prefetch loads stay in flight across it.
#define RAW_BARRIER() do { \
    __builtin_amdgcn_sched_barrier(0); \
    asm volatile("s_waitcnt lgkmcnt(0)" ::: "memory"); \
    __builtin_amdgcn_s_barrier(); \
    __builtin_amdgcn_sched_barrier(0); \
} while (0)

// --- build W_eff = w0 composed with conv, packed in MFMA fragment order ---
// Round-0 layout: Bf[nt][kt][lane][j] = W_eff[nt*16+(lane&15)][kt*32+(lane>>4)*8+j]
__global__ void build_weff(const float* __restrict__ w0, const float* __restrict__ cw,
                           __hip_bfloat16* __restrict__ Bf) {
    int idx = blockIdx.x * blockDim.x + threadIdx.x;
    if (idx >= NT * KT * 512) return;
    int j = idx & 7, L = (idx >> 3) & 63, kt = (idx >> 9) % KT, nt = idx / (KT * 512);
    int n = nt * 16 + (L & 15);
    int k = kt * 32 + ((L >> 4) << 3) + j;
    float acc = 0.f;
    if (n < NH && k < KX) {
        int u = k / IMG, v = k - u * IMG;
#pragma unroll
        for (int i = 0; i < 3; ++i) {
#pragma unroll
            for (int jj = 0; jj < 3; ++jj) {
                int r = u - i, c = v - jj;
                if (r >= 0 && r < 26 && c >= 0 && c < 26)
                    acc += cw[i * 3 + jj] * w0[n * 676 + r * 26 + c];
            }
        }
    }
    Bf[idx] = __float2bfloat16(acc);
}

// f-th float4 of chunk c (row = f/40, chunk-local col4 = f%40); zero for K-pad.
static __device__ __forceinline__ float4 ld_chunk(const float4* __restrict__ xb, int c, int f) {
    int row = f / 40, col4 = f - row * 40;
    int gc4 = c * 40 + col4;                 // global f4 column, 196 = 784/4
    if (gc4 < 196) return xb[row * 196 + gc4];
    return (float4){0.f, 0.f, 0.f, 0.f};    // cols 784..799 pad (chunk 4 only; folded elsewhere)
}

static __device__ __forceinline__ void cvt_store(__hip_bfloat16* __restrict__ Ad, int f, float4 v) {
    int row = f / 40, col4 = f - row * 40;
    s16x4 p;
    p.x = (short)bf16_bits(v.x);
    p.y = (short)bf16_bits(v.y);
    p.z = (short)bf16_bits(v.z);
    p.w = (short)bf16_bits(v.w);
    *(s16x4*)(Ad + row * CHS + col4 * 4) = p;
}

// Chunked pipeline: loads(c+1) -> GEMM(c) -> cvt+ds_write(c+1) -> raw barrier.
// Exactly round-0's GEMM inner codegen (p-ring kt&3, distance 4), 25 kt total.
template <int NTN>
static __device__ __forceinline__ void pipeline(
    const float4* __restrict__ xb, const bf16x8* __restrict__ bb,
    __hip_bfloat16* __restrict__ A0, __hip_bfloat16* __restrict__ A1,
    int tid, int lm, int q, bf16x8 p0[4], bf16x8 p1[4], f32x4 acc[2][2])
{
    float4 v0, v1, v2;
#pragma unroll
    for (int c = 0; c < NCH; ++c) {
        const __hip_bfloat16* Ab = (c & 1) ? A1 : A0;   // consumed this chunk
        __hip_bfloat16* Ad = (c & 1) ? A0 : A1;         // produced for next chunk
        if (c + 1 < NCH) {
            v0 = ld_chunk(xb, c + 1, tid);
            v1 = ld_chunk(xb, c + 1, tid + 512);
            if (tid + 1024 < F4C) v2 = ld_chunk(xb, c + 1, tid + 1024);
            __builtin_amdgcn_sched_barrier(0);   // loads in flight before the GEMM
        }
        const __hip_bfloat16* a0p = Ab + lm * CHS + q * 8;
        const __hip_bfloat16* a1p = Ab + (16 + lm) * CHS + q * 8;
#pragma unroll
        for (int k = 0; k < CHK; ++k) {
            const int kt = c * CHK + k;
            const int slot = kt & 3;
            bf16x8 b0v = p0[slot];
            bf16x8 b1v = p1[slot];
            if (kt + 4 < KT) {
                p0[slot] = bb[(kt + 4) * 64];
                if (NTN == 2) p1[slot] = bb[(KT + kt + 4) * 64];
            }
            bf16x8 af0 = *(const bf16x8*)(a0p + k * 32);
            bf16x8 af1 = *(const bf16x8*)(a1p + k * 32);
            acc[0][0] = __builtin_amdgcn_mfma_f32_16x16x32_bf16(af0, b0v, acc[0][0], 0, 0, 0);
            acc[1][0] = __builtin_amdgcn_mfma_f32_16x16x32_bf16(af1, b0v, acc[1][0], 0, 0, 0);
            if (NTN == 2) {
                acc[0][1] = __builtin_amdgcn_mfma_f32_16x16x32_bf16(af0, b1v, acc[0][1], 0, 0, 0);
                acc[1][1] = __builtin_amdgcn_mfma_f32_16x16x32_bf16(af1, b1v, acc[1][1], 0, 0, 0);
            }
        }
        if (c + 1 < NCH) {
            // vmcnt wait lands HERE (after GEMM): load latency hidden under MFMAs
            cvt_store(Ad, tid, v0);
            cvt_store(Ad, tid + 512, v1);
            if (tid + 1024 < F4C) cvt_store(Ad, tid + 1024, v2);
            RAW_BARRIER();   // identical count (4) in both NTN instantiations
        }
    }
}

// (512,4): round-0's exact resource config (40 VGPR there). 2 blocks/CU.
// LDS: A dbuf 2*32*168*2 = 21,504 + H 32*212*4 = 27,136 -> 48,640 B.
__global__ __launch_bounds__(512, 4) void gemm_fused_kernel(
    const float* __restrict__ x,            // [32768, 784]
    const __hip_bfloat16* __restrict__ Bf,  // fragment-packed W_eff
    const float* __restrict__ b0,           // [200]
    const float* __restrict__ w1,           // [10, 200]
    const float* __restrict__ b1,           // [10]
    float* __restrict__ out)                // [32768, 10]
{
    __shared__ __align__(16) __hip_bfloat16 A[2][MT][CHS];
    __shared__ __align__(16) float H[MT][HSTRIDE];

    const int tid  = threadIdx.x;
    const int wave = tid >> 6;
    const int L    = tid & 63;
    const int lm   = L & 15;
    const int q    = L >> 4;
    const int img0 = blockIdx.x * MT;

    const float4* xb = (const float4*)(x + (size_t)img0 * KX);

    // ---- n-tile ownership: waves {2,2,2,2,2,1,1,1} (round-0) ----
    const int ntbase = (wave < 5) ? wave * 2 : 10 + (wave - 5);
    const int ntn    = (wave < 5) ? 2 : 1;
    const bf16x8* bb = (const bf16x8*)Bf + (size_t)ntbase * KT * 64 + L;

    // ---- prologue: stage chunk 0 -> A[0]; preload B kt=0..3 ----
    {
        float4 v0 = ld_chunk(xb, 0, tid);
        float4 v1 = ld_chunk(xb, 0, tid + 512);
        float4 v2 = (tid + 1024 < F4C) ? ld_chunk(xb, 0, tid + 1024) : (float4){0.f,0.f,0.f,0.f};
        __builtin_amdgcn_sched_barrier(0);
        cvt_store(&A[0][0][0], tid, v0);
        cvt_store(&A[0][0][0], tid + 512, v1);
        if (tid + 1024 < F4C) cvt_store(&A[0][0][0], tid + 1024, v2);
    }
    bf16x8 p0[4], p1[4];
#pragma unroll
    for (int d = 0; d < 4; ++d) {
        p0[d] = bb[d * 64];
        p1[d] = (ntn == 2) ? bb[(KT + d) * 64] : p0[d];
    }
    RAW_BARRIER();   // chunk 0 visible; B preloads stay in flight

    f32x4 acc[2][2];
#pragma unroll
    for (int m = 0; m < 2; ++m)
#pragma unroll
        for (int t = 0; t < 2; ++t) acc[m][t] = (f32x4){0.f, 0.f, 0.f, 0.f};

    if (ntn == 2) pipeline<2>(xb, bb, &A[0][0][0], &A[1][0][0], tid, lm, q, p0, p1, acc);
    else          pipeline<1>(xb, bb, &A[0][0][0], &A[1][0][0], tid, lm, q, p0, p1, acc);

    // ---- epilogue: h = relu(acc + b0) -> H (separate region, no overlay wait) ----
#pragma unroll
    for (int t = 0; t < 2; ++t) {
        if (t < ntn) {
            int n = (ntbase + t) * 16 + lm;
            if (n < NH) {
                float bv = b0[n];
#pragma unroll
                for (int m = 0; m < 2; ++m) {
#pragma unroll
                    for (int r = 0; r < 4; ++r) {
                        int mm = m * 16 + q * 4 + r;
                        float v = acc[m][t][r] + bv;
                        H[mm][n] = v > 0.f ? v : 0.f;
                    }
                }
            }
        }
    }
    RAW_BARRIER();

    // ---- FC1: out = h @ w1.T + b1 (fp32 VALU, 320 results/block) ----
    if (tid < MT * NOUT) {
        int i = tid / NOUT;
        int j = tid - i * NOUT;
        const float4* hrow = (const float4*)(&H[i][0]);
        const float4* wrow = (const float4*)(w1 + j * NH);
        float s = b1[j];
        float4 accv = {0.f, 0.f, 0.f, 0.f};
#pragma unroll 10
        for (int n = 0; n < NH / 4; ++n) {
            float4 h4 = hrow[n];
            float4 w4 = wrow[n];
            accv.x += h4.x * w4.x;
            accv.y += h4.y * w4.y;
            accv.z += h4.z * w4.z;
            accv.w += h4.w * w4.w;
        }
        s += (accv.x + accv.y) + (accv.z + accv.w);
        out[(size_t)(img0 + i) * NOUT + j] = s;
    }
}

extern "C" void kernel_launch(void* const* d_in, const int* in_sizes, int n_in,
                              void* d_out, int out_size, void* d_ws, size_t ws_size,
                              hipStream_t stream) {
    const float* x   = (const float*)d_in[0];
    const float* cw  = (const float*)d_in[1];
    const float* w0  = (const float*)d_in[2];
    const float* b0  = (const float*)d_in[3];
    const float* w1  = (const float*)d_in[4];
    const float* b1  = (const float*)d_in[5];
    float* out = (float*)d_out;

    __hip_bfloat16* Bf = (__hip_bfloat16*)d_ws;  // 13*25*512*2 = 332,800 B

    const int pack_elems = NT * KT * 512;
    build_weff<<<(pack_elems + 255) / 256, 256, 0, stream>>>(w0, cw, Bf);

    gemm_fused_kernel<<<32768 / MT, 512, 0, stream>>>(x, Bf, b0, w1, b1, out);
}